// Round 30
// baseline (743.610 us; speedup 1.0000x reference)
//
#include <hip/hip_runtime.h>
#include <math.h>

#define TWO_PI 6.283185307179586f

// HARNESS MODEL (verified R8-R29): d_out = 33,362,176 f32 = Re(out), [bc][l][m].
// Math: xr[c][k][m] = (2pi/720) * sum_n x[c][k][n] * cos(2pi n m/720)
//       out[c][l][m] = sum_k xr[c][k][m] * W[m][l][k]
// R30 = R28 (best: 543us) with fold_uv MERGED into s2: the A-load phase
// reads forward + mirrored xrp entries (4 predicated u32 loads/thread/iter,
// both coalesced, L2-resident) and the parity fold u/v = x1 +/- x2 plus
// hi/lo split happens in the post-barrier write phase (loads still prefetch
// across the MFMA phase). Kills the ~50us fold kernel + up/vp buffers.
// s1 reverted to R28's staged pipeline (R29 barrier-free regressed 3rd time).

typedef __attribute__((ext_vector_type(8))) short bf16x8;
typedef __attribute__((ext_vector_type(4))) float f32x4;

__device__ inline unsigned short f2bf(float f) {
    union { float f; unsigned int u; } v; v.f = f;
    unsigned int u = v.u;
    return (unsigned short)((u + 0x7fffu + ((u >> 16) & 1u)) >> 16);  // RNE
}
__device__ inline float bf2f(unsigned short h) {
    union { unsigned int u; float f; } v; v.u = ((unsigned int)h) << 16;
    return v.f;
}
__device__ inline unsigned int packhl(float v) {
    unsigned short h = f2bf(v);
    unsigned short l = f2bf(v - bf2f(h));
    return (unsigned int)h | ((unsigned int)l << 16);
}
__device__ inline float unpackhl(unsigned int p) {
    return bf2f((unsigned short)(p & 0xffffu)) + bf2f((unsigned short)(p >> 16));
}
__device__ inline void split2(float a, float b, unsigned int& hh, unsigned int& ll) {
    unsigned short ha = f2bf(a), hb = f2bf(b);
    unsigned short la = f2bf(a - bf2f(ha)), lb = f2bf(b - bf2f(hb));
    hh = (unsigned int)ha | ((unsigned int)hb << 16);
    ll = (unsigned int)la | ((unsigned int)lb << 16);
}
// truncation split (R17/R20-proven for s1 A-path)
__device__ inline void split2t(float a, float b, unsigned int& hh, unsigned int& ll) {
    union { float f; unsigned int u; } ua, ub, fa, fb, la, lb;
    ua.f = a; ub.f = b;
    hh = (ua.u >> 16) | (ub.u & 0xffff0000u);
    fa.u = ua.u & 0xffff0000u;
    fb.u = ub.u & 0xffff0000u;
    la.f = a - fa.f;
    lb.f = b - fb.f;
    ll = (la.u >> 16) | (lb.u & 0xffff0000u);
}
// async global->LDS, 16B per lane; dest = wave-uniform base + lane*16
__device__ inline void gload_lds16(const void* g, void* l) {
    __builtin_amdgcn_global_load_lds(
        (const __attribute__((address_space(1))) unsigned int*)g,
        (__attribute__((address_space(3))) unsigned int*)l, 16, 0, 0);
}
// bijective chunked XCD swizzle (m204)
__device__ inline int xcd_work(int bid, int nwg) {
    int q = nwg >> 3, r = nwg & 7;
    int xcd = bid & 7, ord = bid >> 3;
    return (xcd < r ? xcd * (q + 1) : r * (q + 1) + (xcd - r) * q) + ord;
}

// ---- tables: Eh/El[row=g*192+mg][n<192] bf16, m=2*mg+g, val=sigma*c(n,m),
//      n==180 halved (self-pair), zero for n>180 or m>360 ----
__global__ void build_ect(unsigned short* __restrict__ Eh,
                          unsigned short* __restrict__ El) {
    const float sigma = TWO_PI / 720.0f;
    const int total = 384 * 192;
    for (int i = blockIdx.x * blockDim.x + threadIdx.x; i < total;
         i += gridDim.x * blockDim.x) {
        int row = i / 192, n = i % 192;
        int g = row / 192 ? 1 : 0;
        int mg = row - g * 192;
        int m = 2 * mg + g;
        float v = 0.f;
        if (m <= 360 && n <= 180) {
            int r = (n * m) % 720;  // exact phase reduction
            v = sigma * cosf((float)r * (TWO_PI / 720.0f));
            if (n == 180) v *= 0.5f;
        }
        unsigned short h = f2bf(v);
        Eh[i] = h;
        El[i] = f2bf(v - bf2f(h));
    }
}

// ---------------- stage 1: double-folded DFT, K=192, 6 iterations (R26/R28 proven) ----------------
__global__ __launch_bounds__(256, 4) void s1_mfma(
    const float* __restrict__ x, const unsigned short* __restrict__ Eh,
    const unsigned short* __restrict__ El, unsigned int* __restrict__ xrp,
    const int Q) {
    __shared__ short Ah[2][4][64][8], Al[2][4][64][8];   // 16 KB
    __shared__ short Bt[2][2][4][96][8];                 // 24.5 KB -> 40 KB total

    const int work = xcd_work(blockIdx.x, gridDim.x);
    const int q0 = (work >> 2) * 64;
    const int tt = work & 3;
    const int grp = tt >> 1;           // 0 = even m, 1 = odd m
    const int m0g = (tt & 1) * 96;     // mg tile base
    const int t = threadIdx.x;
    const int lane = t & 63, wv = t >> 6;
    const int lr = lane & 15, lk = lane >> 4;
    const int wq = wv;

    const int ar = t >> 2, akc = t & 3;
    const int aq = q0 + ar;
    const float* arow = x + (size_t)aq * 720;
    const bool aqv = (aq < Q);

    const unsigned short* bsrc[3];
#pragma unroll
    for (int i = 0; i < 3; ++i) {
        int id = t + i * 256;
        int tab = id / 384, rem = id % 384;
        int kc = rem / 96, r = rem % 96;
        bsrc[i] = (tab ? El : Eh) + (size_t)(grp * 192 + m0g + r) * 192 + kc * 8;
    }

    f32x4 acc[6];
#pragma unroll
    for (int nj = 0; nj < 6; ++nj)
#pragma unroll
        for (int r = 0; r < 4; ++r) acc[nj][r] = 0.f;

    float4 f1a, f1b, f2a, f2b, r1a, r1b, r2a, r2b;

#define S1_LOADA(K0)                                                       \
    {                                                                      \
        int kg = (K0) + akc * 8;                                           \
        f1a = make_float4(0.f, 0.f, 0.f, 0.f);                             \
        f1b = f1a; f2a = f1a; f2b = f1a;                                   \
        r1a = f1a; r1b = f1a; r2a = f1a; r2b = f1a;                        \
        if (aqv) {                                                         \
            f1a = *(const float4*)(arow + kg);                             \
            f1b = *(const float4*)(arow + kg + 4);                         \
            f2a = *(const float4*)(arow + 360 + kg);                       \
            f2b = *(const float4*)(arow + 364 + kg);                       \
            r2a = *(const float4*)(arow + 353 - kg);                       \
            r2b = *(const float4*)(arow + 357 - kg);                       \
            if (kg >= 8) {                                                 \
                r1a = *(const float4*)(arow + 713 - kg);                   \
                r1b = *(const float4*)(arow + 717 - kg);                   \
            } else {                                                       \
                float tm[8];                                               \
                _Pragma("unroll") for (int i = 0; i < 8; ++i)              \
                    tm[i] = (7 - i >= 1) ? arow[713 + i] : 0.f;            \
                r1a = make_float4(tm[0], tm[1], tm[2], tm[3]);             \
                r1b = make_float4(tm[4], tm[5], tm[6], tm[7]);             \
            }                                                              \
        }                                                                  \
    }
#define S1_WRITEA(NB, K0)                                                  \
    {                                                                      \
        int kg = (K0) + akc * 8;                                           \
        float b0 = f1a.x + r1b.w, b1 = f1a.y + r1b.z;                      \
        float b2 = f1a.z + r1b.y, b3 = f1a.w + r1b.x;                      \
        float b4 = f1b.x + r1a.w, b5 = f1b.y + r1a.z;                      \
        float b6 = f1b.z + r1a.y, b7 = f1b.w + r1a.x;                      \
        float p0 = r2b.w + ((kg == 0) ? 0.f : f2a.x);                      \
        float p1 = r2b.z + f2a.y, p2 = r2b.y + f2a.z, p3 = r2b.x + f2a.w;  \
        float p4 = r2a.w + f2b.x, p5 = r2a.z + f2b.y;                      \
        float p6 = r2a.y + f2b.z, p7 = r2a.x + f2b.w;                      \
        float s = grp ? -1.f : 1.f;                                        \
        float y0 = b0 + s * p0, y1 = b1 + s * p1;                          \
        float y2 = b2 + s * p2, y3 = b3 + s * p3;                          \
        float y4 = b4 + s * p4, y5 = b5 + s * p5;                          \
        float y6 = b6 + s * p6, y7 = b7 + s * p7;                          \
        if (kg > 172) {                                                    \
            if (kg + 0 > 180) y0 = 0.f;                                    \
            if (kg + 1 > 180) y1 = 0.f;                                    \
            if (kg + 2 > 180) y2 = 0.f;                                    \
            if (kg + 3 > 180) y3 = 0.f;                                    \
            if (kg + 4 > 180) y4 = 0.f;                                    \
            if (kg + 5 > 180) y5 = 0.f;                                    \
            if (kg + 6 > 180) y6 = 0.f;                                    \
            if (kg + 7 > 180) y7 = 0.f;                                    \
        }                                                                  \
        unsigned int h0, h1, h2, h3, l0, l1, l2, l3;                      \
        split2t(y0, y1, h0, l0);                                          \
        split2t(y2, y3, h1, l1);                                          \
        split2t(y4, y5, h2, l2);                                          \
        split2t(y6, y7, h3, l3);                                          \
        *(uint4*)&Ah[NB][akc][ar][0] = make_uint4(h0, h1, h2, h3);        \
        *(uint4*)&Al[NB][akc][ar][0] = make_uint4(l0, l1, l2, l3);        \
    }
#define S1_COPYB(NB, K0)                                                  \
    {                                                                     \
        char* bb = (char*)&Bt[NB][0][0][0][0];                            \
        _Pragma("unroll") for (int i = 0; i < 3; ++i) {                   \
            gload_lds16(bsrc[i] + (K0), bb + (t + i * 256) * 16);         \
        }                                                                 \
    }

    S1_COPYB(0, 0);
    S1_LOADA(0);
    S1_WRITEA(0, 0);
    __syncthreads();
    int cur = 0;
    const int NIT = 6;   // K = 192
    for (int it = 0; it < NIT; ++it) {
        const int nb = cur ^ 1;
        if (it + 1 < NIT) {
            S1_COPYB(nb, (it + 1) * 32);
            S1_LOADA((it + 1) * 32);
        }
        bf16x8 ah = *(const bf16x8*)&Ah[cur][lk][wq * 16 + lr][0];
        bf16x8 al = *(const bf16x8*)&Al[cur][lk][wq * 16 + lr][0];
#pragma unroll
        for (int nj = 0; nj < 6; ++nj) {
            bf16x8 bh = *(const bf16x8*)&Bt[cur][0][lk][nj * 16 + lr][0];
            bf16x8 bl = *(const bf16x8*)&Bt[cur][1][lk][nj * 16 + lr][0];
            acc[nj] = __builtin_amdgcn_mfma_f32_16x16x32_bf16(ah, bh, acc[nj], 0, 0, 0);
            acc[nj] = __builtin_amdgcn_mfma_f32_16x16x32_bf16(ah, bl, acc[nj], 0, 0, 0);
            acc[nj] = __builtin_amdgcn_mfma_f32_16x16x32_bf16(al, bh, acc[nj], 0, 0, 0);
        }
        if (it + 1 < NIT) {
            S1_WRITEA(nb, (it + 1) * 32);
            __syncthreads();
            cur = nb;
        }
    }

#pragma unroll
    for (int nj = 0; nj < 6; ++nj) {
        int mg = m0g + nj * 16 + lr;
        int m = 2 * mg + grp;
        if (m >= 361) continue;
        size_t base = (size_t)m * Q;
#pragma unroll
        for (int reg = 0; reg < 4; ++reg) {
            int q = q0 + wq * 16 + lk * 4 + reg;
            if (q < Q) xrp[base + q] = packhl(acc[nj][reg]);
        }
    }
}

// ---------------- stage 2: parity-folded per-m GEMM with INLINE fold, K=192 ----------------
// 12 blocks/m: 2 bc-halves x 2 parity groups x 3 lg-tiles; l = 2*lg + par.
// A: load xrp fwd (k) + mirrored (360-k); fold u/v = x1 +/- x2 post-barrier.
__global__ __launch_bounds__(256, 4) void s2_mfma(
    const unsigned int* __restrict__ xrp, const float* __restrict__ W,
    float* __restrict__ stg, const int CH) {
    __shared__ short Ah[128][40], Al[128][40];   // 10 KB each
    __shared__ short Bh[64][40], Bl[64][40];     // 5 KB each -> 30 KB

    const int work = xcd_work(blockIdx.x, gridDim.x);
    const int m = work / 12;
    const int rem = work % 12;
    const int half = rem / 6;
    const int r2 = rem % 6;
    const int g = r2 / 3, lgt = r2 % 3;
    const int lg0 = lgt * 64;
    const int par = (g + m) & 1;
    if (2 * (lg0 + 63) + par < m) return;   // dead tile: transpose zero-fills
    const int bcbase = half * 128;
    if (bcbase >= CH) return;
    const int Q = CH * 361;
    const int t = threadIdx.x;
    const int lane = t & 63, wv = t >> 6;
    const int lr = lane & 15, lk = lane >> 4;
    const int wbc = wv >> 1, wl = wv & 1;

    const unsigned int* Am = xrp + (size_t)m * Q;
    const float* Wm = W + (size_t)m * 130321;
    const float sgn = g ? -1.f : 1.f;

    f32x4 acc[4][2];
#pragma unroll
    for (int fi = 0; fi < 4; ++fi)
#pragma unroll
        for (int ni = 0; ni < 2; ++ni)
#pragma unroll
            for (int r = 0; r < 4; ++r) acc[fi][ni][r] = 0.f;

    unsigned int paf0[8], paf1[8], par0[8], par1[8];   // fwd/rev raw prefetch
    float wva[4], wvb[4];

#define S2_LOADR(K0)                                                          \
    {                                                                         \
        _Pragma("unroll") for (int i = 0; i < 8; ++i) {                       \
            int id = t + i * 256;                                             \
            int r = id >> 4, kp = id & 15;                                    \
            int bc = bcbase + r, kg = (K0) + kp * 2;                          \
            unsigned int f0 = 0, f1 = 0, v0 = 0, v1 = 0;                      \
            if (bc < CH) {                                                    \
                size_t base = (size_t)bc * 361;                               \
                if (kg <= 180) {                                              \
                    f0 = Am[base + kg];                                       \
                    if (kg < 180) v0 = Am[base + 360 - kg];                   \
                }                                                             \
                if (kg + 1 <= 180) {                                          \
                    f1 = Am[base + kg + 1];                                   \
                    if (kg + 1 < 180) v1 = Am[base + 359 - kg];               \
                }                                                             \
            }                                                                 \
            paf0[i] = f0; paf1[i] = f1; par0[i] = v0; par1[i] = v1;           \
        }                                                                     \
        _Pragma("unroll") for (int i = 0; i < 4; ++i) {                       \
            int id = t + i * 256;                                             \
            int r = id >> 4, kp = id & 15;                                    \
            int l = 2 * (lg0 + r) + par, kg = (K0) + kp * 2;                  \
            float va = 0.f, vb = 0.f;                                         \
            if (l < 361) {                                                    \
                size_t base = (size_t)l * 361;                                \
                if (kg <= 180) va = Wm[base + kg];                            \
                if (kg + 1 <= 180) vb = Wm[base + kg + 1];                    \
            }                                                                 \
            wva[i] = va; wvb[i] = vb;                                         \
        }                                                                     \
    }
#define S2_WRITES()                                                           \
    {                                                                         \
        _Pragma("unroll") for (int i = 0; i < 8; ++i) {                       \
            int id = t + i * 256;                                             \
            int r = id >> 4, kp = id & 15;                                    \
            float u0 = unpackhl(paf0[i]) + sgn * unpackhl(par0[i]);           \
            float u1 = unpackhl(paf1[i]) + sgn * unpackhl(par1[i]);           \
            unsigned int hh, ll;                                              \
            split2(u0, u1, hh, ll);                                           \
            *(unsigned int*)&Ah[r][kp * 2] = hh;                              \
            *(unsigned int*)&Al[r][kp * 2] = ll;                              \
        }                                                                     \
        _Pragma("unroll") for (int i = 0; i < 4; ++i) {                       \
            int id = t + i * 256;                                             \
            int r = id >> 4, kp = id & 15;                                    \
            unsigned int hh, ll;                                              \
            split2(wva[i], wvb[i], hh, ll);                                   \
            *(unsigned int*)&Bh[r][kp * 2] = hh;                              \
            *(unsigned int*)&Bl[r][kp * 2] = ll;                              \
        }                                                                     \
    }

    S2_LOADR(0);
    S2_WRITES();
    __syncthreads();
    for (int it = 0; it < 6; ++it) {
        if (it + 1 < 6) S2_LOADR((it + 1) * 32);
#pragma unroll
        for (int fi = 0; fi < 4; ++fi) {
            bf16x8 ah = *(const bf16x8*)&Ah[wbc * 64 + fi * 16 + lr][lk * 8];
            bf16x8 al = *(const bf16x8*)&Al[wbc * 64 + fi * 16 + lr][lk * 8];
#pragma unroll
            for (int ni = 0; ni < 2; ++ni) {
                bf16x8 bh = *(const bf16x8*)&Bh[wl * 32 + ni * 16 + lr][lk * 8];
                bf16x8 bl = *(const bf16x8*)&Bl[wl * 32 + ni * 16 + lr][lk * 8];
                acc[fi][ni] = __builtin_amdgcn_mfma_f32_16x16x32_bf16(ah, bh, acc[fi][ni], 0, 0, 0);
                acc[fi][ni] = __builtin_amdgcn_mfma_f32_16x16x32_bf16(ah, bl, acc[fi][ni], 0, 0, 0);
                acc[fi][ni] = __builtin_amdgcn_mfma_f32_16x16x32_bf16(al, bh, acc[fi][ni], 0, 0, 0);
            }
        }
        __syncthreads();
        if (it + 1 < 6) {
            S2_WRITES();
            __syncthreads();
        }
    }

    // epilogue: stg[(m*CH+bc)*361 + l],  l = 2*(lg0+row)+par
#pragma unroll
    for (int fi = 0; fi < 4; ++fi) {
#pragma unroll
        for (int ni = 0; ni < 2; ++ni) {
            int l = 2 * (lg0 + wl * 32 + ni * 16 + lr) + par;
#pragma unroll
            for (int reg = 0; reg < 4; ++reg) {
                int bc = bcbase + wbc * 64 + fi * 16 + lk * 4 + reg;
                if (bc < CH && l < 361)
                    stg[((size_t)m * CH + bc) * 361 + l] = acc[fi][ni][reg];
            }
        }
    }
}

// ---------------- transpose stg [m][q'] -> out, zero-filling dead parity-tiles ----------------
__global__ __launch_bounds__(256) void transpose_out(const float* __restrict__ stg,
                                                     float* __restrict__ out,
                                                     const int c0, const int CH) {
    __shared__ float tile[32][33];
    const int Q = CH * 361;
    const int m0 = blockIdx.y * 32, q0 = blockIdx.x * 32;
    const int tx = threadIdx.x & 31, ty = threadIdx.x >> 5;
    for (int i = ty; i < 32; i += 8) {
        int mm = m0 + i, q = q0 + tx;
        float v = 0.f;
        if (mm < 361 && q < Q) {
            int l = q % 361;
            int par = l & 1;          // parity of l indexes the s2 tile (R28 fix)
            int lg = l >> 1;
            if (2 * (lg | 63) + par >= mm) v = stg[(size_t)mm * Q + q];
        }
        tile[i][tx] = v;
    }
    __syncthreads();
    for (int i = ty; i < 32; i += 8) {
        int q = q0 + i, mm = m0 + tx;
        if (mm < 361 && q < Q)
            out[((size_t)c0 * 361 + q) * 361 + mm] = tile[tx][i];
    }
}

extern "C" void kernel_launch(void* const* d_in, const int* in_sizes, int n_in,
                              void* d_out, int out_size, void* d_ws, size_t ws_size,
                              hipStream_t stream) {
    (void)out_size;
    // select inputs by element count: x = 66,539,520; W = 47,045,881
    const float* x = (const float*)d_in[0];
    const float* W = (const float*)d_in[1];
    if (n_in >= 2 && (in_sizes[0] == 47045881 || in_sizes[1] == 66539520)) {
        x = (const float*)d_in[1];
        W = (const float*)d_in[0];
    }
    float* out = (float*)d_out;

    // ws layout (bytes): Eh [384][192] | El | xrp (u32) | stg (f32)
    const size_t offEh = 0;
    const size_t offEl = 147456;                 // 384*192*2
    const size_t offData = 294912;

    const int cands[6] = {256, 128, 64, 32, 16, 8};
    int CH = 0;
    for (int i = 0; i < 6; ++i) {
        size_t need = offData + (size_t)cands[i] * (130321ull * 2) * 4;
        if (need <= ws_size) { CH = cands[i]; break; }
    }
    if (!CH) return;  // workspace too small: fail visibly, don't fault

    unsigned short* Eh = (unsigned short*)((char*)d_ws + offEh);
    unsigned short* El = (unsigned short*)((char*)d_ws + offEl);
    unsigned int* xrp = (unsigned int*)((char*)d_ws + offData);
    float* stg = (float*)(xrp + (size_t)CH * 130321);

    build_ect<<<256, 256, 0, stream>>>(Eh, El);

    const int Q = CH * 361;
    const int qt = (Q + 63) / 64;
    for (int c0 = 0; c0 < 256; c0 += CH) {
        s1_mfma<<<qt * 4, 256, 0, stream>>>(
            x + (size_t)c0 * 361 * 720, Eh, El, xrp, Q);
        s2_mfma<<<361 * 12, 256, 0, stream>>>(xrp, W, stg, CH);
        transpose_out<<<dim3((Q + 31) / 32, 12), 256, 0, stream>>>(stg, out, c0, CH);
    }
}

// Round 31
// 542.637 us; speedup vs baseline: 1.3704x; 1.3704x over previous
//
#include <hip/hip_runtime.h>
#include <math.h>

#define TWO_PI 6.283185307179586f

// HARNESS MODEL (verified R8-R30): d_out = 33,362,176 f32 = Re(out), [bc][l][m].
// Math: xr[c][k][m] = (2pi/720) * sum_n x[c][k][n] * cos(2pi n m/720)
//       out[c][l][m] = sum_k xr[c][k][m] * W[m][l][k]
// R31 = R28 VERBATIM (best measured: 543us, absmax at ref floor).
// R30's merged fold spilled (40 cross-barrier regs -> 332MB scratch writes);
// rule confirmed 3x (R11/R13/R30): keep cross-barrier prefetch <= ~24 regs.
// Structure: s1 = double-folded DFT (K=192, 6 iters, R20 pipeline);
// fold_uv separate; s2 = parity-folded GEMM (K=192, 6 iters); transpose.

typedef __attribute__((ext_vector_type(8))) short bf16x8;
typedef __attribute__((ext_vector_type(4))) float f32x4;

__device__ inline unsigned short f2bf(float f) {
    union { float f; unsigned int u; } v; v.f = f;
    unsigned int u = v.u;
    return (unsigned short)((u + 0x7fffu + ((u >> 16) & 1u)) >> 16);  // RNE
}
__device__ inline float bf2f(unsigned short h) {
    union { unsigned int u; float f; } v; v.u = ((unsigned int)h) << 16;
    return v.f;
}
__device__ inline unsigned int packhl(float v) {
    unsigned short h = f2bf(v);
    unsigned short l = f2bf(v - bf2f(h));
    return (unsigned int)h | ((unsigned int)l << 16);
}
__device__ inline float unpackhl(unsigned int p) {
    return bf2f((unsigned short)(p & 0xffffu)) + bf2f((unsigned short)(p >> 16));
}
__device__ inline void split2(float a, float b, unsigned int& hh, unsigned int& ll) {
    unsigned short ha = f2bf(a), hb = f2bf(b);
    unsigned short la = f2bf(a - bf2f(ha)), lb = f2bf(b - bf2f(hb));
    hh = (unsigned int)ha | ((unsigned int)hb << 16);
    ll = (unsigned int)la | ((unsigned int)lb << 16);
}
// truncation split (R17/R20-proven for s1 A-path)
__device__ inline void split2t(float a, float b, unsigned int& hh, unsigned int& ll) {
    union { float f; unsigned int u; } ua, ub, fa, fb, la, lb;
    ua.f = a; ub.f = b;
    hh = (ua.u >> 16) | (ub.u & 0xffff0000u);
    fa.u = ua.u & 0xffff0000u;
    fb.u = ub.u & 0xffff0000u;
    la.f = a - fa.f;
    lb.f = b - fb.f;
    ll = (la.u >> 16) | (lb.u & 0xffff0000u);
}
// async global->LDS, 16B per lane; dest = wave-uniform base + lane*16
__device__ inline void gload_lds16(const void* g, void* l) {
    __builtin_amdgcn_global_load_lds(
        (const __attribute__((address_space(1))) unsigned int*)g,
        (__attribute__((address_space(3))) unsigned int*)l, 16, 0, 0);
}
// bijective chunked XCD swizzle (m204)
__device__ inline int xcd_work(int bid, int nwg) {
    int q = nwg >> 3, r = nwg & 7;
    int xcd = bid & 7, ord = bid >> 3;
    return (xcd < r ? xcd * (q + 1) : r * (q + 1) + (xcd - r) * q) + ord;
}

// ---- tables: Eh/El[row=g*192+mg][n<192] bf16, m=2*mg+g, val=sigma*c(n,m),
//      n==180 halved (self-pair), zero for n>180 or m>360 ----
__global__ void build_ect(unsigned short* __restrict__ Eh,
                          unsigned short* __restrict__ El) {
    const float sigma = TWO_PI / 720.0f;
    const int total = 384 * 192;
    for (int i = blockIdx.x * blockDim.x + threadIdx.x; i < total;
         i += gridDim.x * blockDim.x) {
        int row = i / 192, n = i % 192;
        int g = row / 192 ? 1 : 0;
        int mg = row - g * 192;
        int m = 2 * mg + g;
        float v = 0.f;
        if (m <= 360 && n <= 180) {
            int r = (n * m) % 720;  // exact phase reduction
            v = sigma * cosf((float)r * (TWO_PI / 720.0f));
            if (n == 180) v *= 0.5f;
        }
        unsigned short h = f2bf(v);
        Eh[i] = h;
        El[i] = f2bf(v - bf2f(h));
    }
}

// ---------------- stage 1: double-folded DFT, K=192, 6 iterations ----------------
__global__ __launch_bounds__(256, 4) void s1_mfma(
    const float* __restrict__ x, const unsigned short* __restrict__ Eh,
    const unsigned short* __restrict__ El, unsigned int* __restrict__ xrp,
    const int Q) {
    __shared__ short Ah[2][4][64][8], Al[2][4][64][8];   // 16 KB
    __shared__ short Bt[2][2][4][96][8];                 // 24.5 KB -> 40 KB total

    const int work = xcd_work(blockIdx.x, gridDim.x);
    const int q0 = (work >> 2) * 64;
    const int tt = work & 3;
    const int grp = tt >> 1;           // 0 = even m, 1 = odd m
    const int m0g = (tt & 1) * 96;     // mg tile base
    const int t = threadIdx.x;
    const int lane = t & 63, wv = t >> 6;
    const int lr = lane & 15, lk = lane >> 4;
    const int wq = wv;

    const int ar = t >> 2, akc = t & 3;
    const int aq = q0 + ar;
    const float* arow = x + (size_t)aq * 720;
    const bool aqv = (aq < Q);

    const unsigned short* bsrc[3];
#pragma unroll
    for (int i = 0; i < 3; ++i) {
        int id = t + i * 256;
        int tab = id / 384, rem = id % 384;
        int kc = rem / 96, r = rem % 96;
        bsrc[i] = (tab ? El : Eh) + (size_t)(grp * 192 + m0g + r) * 192 + kc * 8;
    }

    f32x4 acc[6];
#pragma unroll
    for (int nj = 0; nj < 6; ++nj)
#pragma unroll
        for (int r = 0; r < 4; ++r) acc[nj][r] = 0.f;

    float4 f1a, f1b, f2a, f2b, r1a, r1b, r2a, r2b;

#define S1_LOADA(K0)                                                       \
    {                                                                      \
        int kg = (K0) + akc * 8;                                           \
        f1a = make_float4(0.f, 0.f, 0.f, 0.f);                             \
        f1b = f1a; f2a = f1a; f2b = f1a;                                   \
        r1a = f1a; r1b = f1a; r2a = f1a; r2b = f1a;                        \
        if (aqv) {                                                         \
            f1a = *(const float4*)(arow + kg);                             \
            f1b = *(const float4*)(arow + kg + 4);                         \
            f2a = *(const float4*)(arow + 360 + kg);                       \
            f2b = *(const float4*)(arow + 364 + kg);                       \
            r2a = *(const float4*)(arow + 353 - kg);                       \
            r2b = *(const float4*)(arow + 357 - kg);                       \
            if (kg >= 8) {                                                 \
                r1a = *(const float4*)(arow + 713 - kg);                   \
                r1b = *(const float4*)(arow + 717 - kg);                   \
            } else {                                                       \
                float tm[8];                                               \
                _Pragma("unroll") for (int i = 0; i < 8; ++i)              \
                    tm[i] = (7 - i >= 1) ? arow[713 + i] : 0.f;            \
                r1a = make_float4(tm[0], tm[1], tm[2], tm[3]);             \
                r1b = make_float4(tm[4], tm[5], tm[6], tm[7]);             \
            }                                                              \
        }                                                                  \
    }
#define S1_WRITEA(NB, K0)                                                  \
    {                                                                      \
        int kg = (K0) + akc * 8;                                           \
        float b0 = f1a.x + r1b.w, b1 = f1a.y + r1b.z;                      \
        float b2 = f1a.z + r1b.y, b3 = f1a.w + r1b.x;                      \
        float b4 = f1b.x + r1a.w, b5 = f1b.y + r1a.z;                      \
        float b6 = f1b.z + r1a.y, b7 = f1b.w + r1a.x;                      \
        float p0 = r2b.w + ((kg == 0) ? 0.f : f2a.x);                      \
        float p1 = r2b.z + f2a.y, p2 = r2b.y + f2a.z, p3 = r2b.x + f2a.w;  \
        float p4 = r2a.w + f2b.x, p5 = r2a.z + f2b.y;                      \
        float p6 = r2a.y + f2b.z, p7 = r2a.x + f2b.w;                      \
        float s = grp ? -1.f : 1.f;                                        \
        float y0 = b0 + s * p0, y1 = b1 + s * p1;                          \
        float y2 = b2 + s * p2, y3 = b3 + s * p3;                          \
        float y4 = b4 + s * p4, y5 = b5 + s * p5;                          \
        float y6 = b6 + s * p6, y7 = b7 + s * p7;                          \
        if (kg > 172) {                                                    \
            if (kg + 0 > 180) y0 = 0.f;                                    \
            if (kg + 1 > 180) y1 = 0.f;                                    \
            if (kg + 2 > 180) y2 = 0.f;                                    \
            if (kg + 3 > 180) y3 = 0.f;                                    \
            if (kg + 4 > 180) y4 = 0.f;                                    \
            if (kg + 5 > 180) y5 = 0.f;                                    \
            if (kg + 6 > 180) y6 = 0.f;                                    \
            if (kg + 7 > 180) y7 = 0.f;                                    \
        }                                                                  \
        unsigned int h0, h1, h2, h3, l0, l1, l2, l3;                      \
        split2t(y0, y1, h0, l0);                                          \
        split2t(y2, y3, h1, l1);                                          \
        split2t(y4, y5, h2, l2);                                          \
        split2t(y6, y7, h3, l3);                                          \
        *(uint4*)&Ah[NB][akc][ar][0] = make_uint4(h0, h1, h2, h3);        \
        *(uint4*)&Al[NB][akc][ar][0] = make_uint4(l0, l1, l2, l3);        \
    }
#define S1_COPYB(NB, K0)                                                  \
    {                                                                     \
        char* bb = (char*)&Bt[NB][0][0][0][0];                            \
        _Pragma("unroll") for (int i = 0; i < 3; ++i) {                   \
            gload_lds16(bsrc[i] + (K0), bb + (t + i * 256) * 16);         \
        }                                                                 \
    }

    S1_COPYB(0, 0);
    S1_LOADA(0);
    S1_WRITEA(0, 0);
    __syncthreads();
    int cur = 0;
    const int NIT = 6;   // K = 192
    for (int it = 0; it < NIT; ++it) {
        const int nb = cur ^ 1;
        if (it + 1 < NIT) {
            S1_COPYB(nb, (it + 1) * 32);
            S1_LOADA((it + 1) * 32);
        }
        bf16x8 ah = *(const bf16x8*)&Ah[cur][lk][wq * 16 + lr][0];
        bf16x8 al = *(const bf16x8*)&Al[cur][lk][wq * 16 + lr][0];
#pragma unroll
        for (int nj = 0; nj < 6; ++nj) {
            bf16x8 bh = *(const bf16x8*)&Bt[cur][0][lk][nj * 16 + lr][0];
            bf16x8 bl = *(const bf16x8*)&Bt[cur][1][lk][nj * 16 + lr][0];
            acc[nj] = __builtin_amdgcn_mfma_f32_16x16x32_bf16(ah, bh, acc[nj], 0, 0, 0);
            acc[nj] = __builtin_amdgcn_mfma_f32_16x16x32_bf16(ah, bl, acc[nj], 0, 0, 0);
            acc[nj] = __builtin_amdgcn_mfma_f32_16x16x32_bf16(al, bh, acc[nj], 0, 0, 0);
        }
        if (it + 1 < NIT) {
            S1_WRITEA(nb, (it + 1) * 32);
            __syncthreads();
            cur = nb;
        }
    }

#pragma unroll
    for (int nj = 0; nj < 6; ++nj) {
        int mg = m0g + nj * 16 + lr;
        int m = 2 * mg + grp;
        if (m >= 361) continue;
        size_t base = (size_t)m * Q;
#pragma unroll
        for (int reg = 0; reg < 4; ++reg) {
            int q = q0 + wq * 16 + lk * 4 + reg;
            if (q < Q) xrp[base + q] = packhl(acc[nj][reg]);
        }
    }
}

// ---------------- fold_uv: u/v packed planes [m][bc][192] from xrp ----------------
__global__ __launch_bounds__(256) void fold_uv(const unsigned int* __restrict__ xrp,
                                               unsigned int* __restrict__ up,
                                               unsigned int* __restrict__ vp,
                                               const int CH) {
    const int total = 361 * CH * 192;
    const int Q = CH * 361;
    for (int i = blockIdx.x * blockDim.x + threadIdx.x; i < total;
         i += gridDim.x * blockDim.x) {
        int m = i / (CH * 192);
        int rem = i - m * (CH * 192);
        int bc = rem / 192;
        int k = rem - bc * 192;
        float u = 0.f, v = 0.f;
        if (k <= 180) {
            size_t base = (size_t)m * Q + (size_t)bc * 361;
            float x1 = unpackhl(xrp[base + k]);
            if (k < 180) {
                float x2 = unpackhl(xrp[base + 360 - k]);
                u = x1 + x2;
                v = x1 - x2;
            } else {
                u = x1;
                v = x1;
            }
        }
        up[i] = packhl(u);
        vp[i] = packhl(v);
    }
}

// ---------------- stage 2: parity-folded per-m GEMM, K=192 (6 iters) ----------------
// 12 blocks/m: 2 bc-halves x 2 parity groups x 3 lg-tiles; l = 2*lg + par.
__global__ __launch_bounds__(256, 4) void s2_mfma(
    const unsigned int* __restrict__ up, const unsigned int* __restrict__ vp,
    const float* __restrict__ W, float* __restrict__ stg, const int CH) {
    __shared__ short Ah[128][40], Al[128][40];   // 10 KB each
    __shared__ short Bh[64][40], Bl[64][40];     // 5 KB each -> 30 KB

    const int work = xcd_work(blockIdx.x, gridDim.x);
    const int m = work / 12;
    const int rem = work % 12;
    const int half = rem / 6;
    const int r2 = rem % 6;
    const int g = r2 / 3, lgt = r2 % 3;
    const int lg0 = lgt * 64;
    const int par = (g + m) & 1;
    if (2 * (lg0 + 63) + par < m) return;   // dead tile: transpose zero-fills
    const int bcbase = half * 128;
    if (bcbase >= CH) return;
    const int t = threadIdx.x;
    const int lane = t & 63, wv = t >> 6;
    const int lr = lane & 15, lk = lane >> 4;
    const int wbc = wv >> 1, wl = wv & 1;

    const unsigned int* Am = (g ? vp : up) + (size_t)m * CH * 192;
    const float* Wm = W + (size_t)m * 130321;

    f32x4 acc[4][2];
#pragma unroll
    for (int fi = 0; fi < 4; ++fi)
#pragma unroll
        for (int ni = 0; ni < 2; ++ni)
#pragma unroll
            for (int r = 0; r < 4; ++r) acc[fi][ni][r] = 0.f;

    unsigned int pa0[8], pa1[8];
    float wva[4], wvb[4];

#define S2_LOADR(K0)                                                          \
    {                                                                         \
        _Pragma("unroll") for (int i = 0; i < 8; ++i) {                       \
            int id = t + i * 256;                                             \
            int r = id >> 4, kp = id & 15;                                    \
            int bc = bcbase + r, kg = (K0) + kp * 2;                          \
            unsigned int p0 = 0, p1 = 0;                                      \
            if (bc < CH) {                                                    \
                size_t base = (size_t)bc * 192;                               \
                p0 = Am[base + kg];                                           \
                p1 = Am[base + kg + 1];                                       \
            }                                                                 \
            pa0[i] = p0; pa1[i] = p1;                                         \
        }                                                                     \
        _Pragma("unroll") for (int i = 0; i < 4; ++i) {                       \
            int id = t + i * 256;                                             \
            int r = id >> 4, kp = id & 15;                                    \
            int l = 2 * (lg0 + r) + par, kg = (K0) + kp * 2;                  \
            float va = 0.f, vb = 0.f;                                         \
            if (l < 361) {                                                    \
                size_t base = (size_t)l * 361;                                \
                if (kg <= 180) va = Wm[base + kg];                            \
                if (kg + 1 <= 180) vb = Wm[base + kg + 1];                    \
            }                                                                 \
            wva[i] = va; wvb[i] = vb;                                         \
        }                                                                     \
    }
#define S2_WRITES()                                                           \
    {                                                                         \
        _Pragma("unroll") for (int i = 0; i < 8; ++i) {                       \
            int id = t + i * 256;                                             \
            int r = id >> 4, kp = id & 15;                                    \
            *(unsigned int*)&Ah[r][kp * 2] =                                  \
                (pa0[i] & 0xffffu) | (pa1[i] << 16);                          \
            *(unsigned int*)&Al[r][kp * 2] =                                  \
                (pa0[i] >> 16) | (pa1[i] & 0xffff0000u);                      \
        }                                                                     \
        _Pragma("unroll") for (int i = 0; i < 4; ++i) {                       \
            int id = t + i * 256;                                             \
            int r = id >> 4, kp = id & 15;                                    \
            unsigned int hh, ll;                                              \
            split2(wva[i], wvb[i], hh, ll);                                   \
            *(unsigned int*)&Bh[r][kp * 2] = hh;                              \
            *(unsigned int*)&Bl[r][kp * 2] = ll;                              \
        }                                                                     \
    }

    S2_LOADR(0);
    S2_WRITES();
    __syncthreads();
    for (int it = 0; it < 6; ++it) {
        if (it + 1 < 6) S2_LOADR((it + 1) * 32);
#pragma unroll
        for (int fi = 0; fi < 4; ++fi) {
            bf16x8 ah = *(const bf16x8*)&Ah[wbc * 64 + fi * 16 + lr][lk * 8];
            bf16x8 al = *(const bf16x8*)&Al[wbc * 64 + fi * 16 + lr][lk * 8];
#pragma unroll
            for (int ni = 0; ni < 2; ++ni) {
                bf16x8 bh = *(const bf16x8*)&Bh[wl * 32 + ni * 16 + lr][lk * 8];
                bf16x8 bl = *(const bf16x8*)&Bl[wl * 32 + ni * 16 + lr][lk * 8];
                acc[fi][ni] = __builtin_amdgcn_mfma_f32_16x16x32_bf16(ah, bh, acc[fi][ni], 0, 0, 0);
                acc[fi][ni] = __builtin_amdgcn_mfma_f32_16x16x32_bf16(ah, bl, acc[fi][ni], 0, 0, 0);
                acc[fi][ni] = __builtin_amdgcn_mfma_f32_16x16x32_bf16(al, bh, acc[fi][ni], 0, 0, 0);
            }
        }
        __syncthreads();
        if (it + 1 < 6) {
            S2_WRITES();
            __syncthreads();
        }
    }

    // epilogue: stg[(m*CH+bc)*361 + l],  l = 2*(lg0+row)+par
#pragma unroll
    for (int fi = 0; fi < 4; ++fi) {
#pragma unroll
        for (int ni = 0; ni < 2; ++ni) {
            int l = 2 * (lg0 + wl * 32 + ni * 16 + lr) + par;
#pragma unroll
            for (int reg = 0; reg < 4; ++reg) {
                int bc = bcbase + wbc * 64 + fi * 16 + lk * 4 + reg;
                if (bc < CH && l < 361)
                    stg[((size_t)m * CH + bc) * 361 + l] = acc[fi][ni][reg];
            }
        }
    }
}

// ---------------- transpose stg [m][q'] -> out, zero-filling dead parity-tiles ----------------
__global__ __launch_bounds__(256) void transpose_out(const float* __restrict__ stg,
                                                     float* __restrict__ out,
                                                     const int c0, const int CH) {
    __shared__ float tile[32][33];
    const int Q = CH * 361;
    const int m0 = blockIdx.y * 32, q0 = blockIdx.x * 32;
    const int tx = threadIdx.x & 31, ty = threadIdx.x >> 5;
    for (int i = ty; i < 32; i += 8) {
        int mm = m0 + i, q = q0 + tx;
        float v = 0.f;
        if (mm < 361 && q < Q) {
            int l = q % 361;
            int par = l & 1;          // parity of l indexes the s2 tile (R28 fix)
            int lg = l >> 1;
            if (2 * (lg | 63) + par >= mm) v = stg[(size_t)mm * Q + q];
        }
        tile[i][tx] = v;
    }
    __syncthreads();
    for (int i = ty; i < 32; i += 8) {
        int q = q0 + i, mm = m0 + tx;
        if (mm < 361 && q < Q)
            out[((size_t)c0 * 361 + q) * 361 + mm] = tile[tx][i];
    }
}

extern "C" void kernel_launch(void* const* d_in, const int* in_sizes, int n_in,
                              void* d_out, int out_size, void* d_ws, size_t ws_size,
                              hipStream_t stream) {
    (void)out_size;
    // select inputs by element count: x = 66,539,520; W = 47,045,881
    const float* x = (const float*)d_in[0];
    const float* W = (const float*)d_in[1];
    if (n_in >= 2 && (in_sizes[0] == 47045881 || in_sizes[1] == 66539520)) {
        x = (const float*)d_in[1];
        W = (const float*)d_in[0];
    }
    float* out = (float*)d_out;

    // ws layout (bytes): Eh [384][192] | El | xrp | up | vp | stg
    const size_t offEh = 0;
    const size_t offEl = 147456;                 // 384*192*2
    const size_t offData = 294912;

    // per-CH elements: xrp CH*130321 u32; up/vp CH*69312 u32 each; stg CH*130321 f32
    const int cands[6] = {256, 128, 64, 32, 16, 8};
    int CH = 0;
    for (int i = 0; i < 6; ++i) {
        size_t need = offData + (size_t)cands[i] * (130321ull * 2 + 69312ull * 2) * 4;
        if (need <= ws_size) { CH = cands[i]; break; }
    }
    if (!CH) return;  // workspace too small: fail visibly, don't fault

    unsigned short* Eh = (unsigned short*)((char*)d_ws + offEh);
    unsigned short* El = (unsigned short*)((char*)d_ws + offEl);
    unsigned int* xrp = (unsigned int*)((char*)d_ws + offData);
    unsigned int* up = xrp + (size_t)CH * 130321;
    unsigned int* vp = up + (size_t)CH * 69312;
    float* stg = (float*)(vp + (size_t)CH * 69312);

    build_ect<<<256, 256, 0, stream>>>(Eh, El);

    const int Q = CH * 361;
    const int qt = (Q + 63) / 64;
    for (int c0 = 0; c0 < 256; c0 += CH) {
        s1_mfma<<<qt * 4, 256, 0, stream>>>(
            x + (size_t)c0 * 361 * 720, Eh, El, xrp, Q);
        fold_uv<<<8192, 256, 0, stream>>>(xrp, up, vp, CH);
        s2_mfma<<<361 * 12, 256, 0, stream>>>(up, vp, W, stg, CH);
        transpose_out<<<dim3((Q + 31) / 32, 12), 256, 0, stream>>>(stg, out, c0, CH);
    }
}